// Round 7
// baseline (453.594 us; speedup 1.0000x reference)
//
#include <hip/hip_runtime.h>

// SSIM loss, two-pass separable conv through LDS. 96 planes of 512x512.
// R11: 64x16 tile, 256-thread blocks (8 blocks/CU), batched pass-1 loads.
//
// R10 post-mortem: (4,8) gave clean codegen but allocator squeezed to 36
// VGPRs -> pass-1's 28 independent loads issue in ~5-load batches, each
// thread serializes a 14-deep load->FMA chain against memory latency;
// 512-thread blocks at the 2048-thread/CU cap convoy on the mid-kernel
// barrier (Occupancy 62%). VALU real work is 86us (constant since R9);
// dur 227us = issue stalls.
//
// R11 changes:
//  * Tile 64x16, 256 threads: hbuf = 16 x stride75 x float4 = 19.2KB ->
//    8 blocks/CU x 4 waves = 32 waves/CU. Finer blocks stagger barriers
//    and pass-1 bursts across 8 independent blocks.
//  * Pass 1 loads batched: xs[14]/ys[14] arrays (statically indexed ->
//    registers), ALL loads issued before the FMA sweep. Peak live ~55
//    VGPRs - fits the 64-reg/8-waves-per-EU budget while giving 28
//    loads in flight per thread.
//  * Interior fast path (wave-uniform for ~70% of tiles): unconditional
//    stride-IMG loads, no per-row cndmask.
//
// Layout (verified R6-R10): h buffer [16][stride 75] float4
// {convV(s),convV(d),convV(s^2),convV(d^2)}; odd stride -> conflict-free
// b128 reads (8-lane phase groups hit 8 distinct bank-quads) and writes.

typedef float v2f __attribute__((ext_vector_type(2)));
typedef float v4f __attribute__((ext_vector_type(4)));

#define IMG 512
#define TW 64               // tile width  (output cols)
#define TH 16               // tile height (output rows)
#define HALO 5
#define HCOLS 74            // TW + 2*HALO columns of h
#define HSTRIDE 75          // in float4 units; odd -> conflict-free
#define RPT1 4              // pass-1 output rows per unit
#define SEGS 4              // TH / RPT1
#define NROWS 14            // input rows per pass-1 unit (RPT1 + 10)
#define NPIX 25165824.0     // 32*3*512*512

// Gaussian(sigma=1.5, 11 taps), normalized, fp32 (verified R1-R10)
__device__ constexpr float WT[11] = {
    0.00102838f, 0.00759876f, 0.03600077f, 0.10936068f, 0.21300552f,
    0.26601173f,
    0.21300552f, 0.10936068f, 0.03600077f, 0.00759876f, 0.00102838f};

__global__ __launch_bounds__(256)
__attribute__((amdgpu_waves_per_eu(4, 8)))
void ssim_main(const float* __restrict__ clean,
               const float* __restrict__ adv,
               double* __restrict__ accum)
{
    // h[row][col]: float4 {convV(s), convV(d), convV(s^2), convV(d^2)}
    __shared__ __align__(16) v4f hbuf[TH * HSTRIDE];   // 19,200 B
    __shared__ float wpart[4];

    const int tid = threadIdx.x;
    const int b = blockIdx.x;
    const int plane = b >> 8;             // 256 tiles per plane
    const int t8 = b & 255;
    const int tile_x = (t8 & 7) * TW;     // 8 tiles across
    const int tile_y = (t8 >> 3) * TH;    // 32 tiles down

    const float* __restrict__ cp = clean + (size_t)plane * (IMG * IMG);
    const float* __restrict__ ap = adv   + (size_t)plane * (IMG * IMG);

    // ---- Pass 1: vertical conv, global -> LDS ----
    // unit u: seg = u/74 (output rows seg*4..seg*4+3), uc = u%74
    // (image col tile_x + uc - 5). Consecutive lanes -> consecutive
    // columns -> coalesced. Threads 0..39 take a second unit.
    for (int u = tid; u < HCOLS * SEGS; u += 256) {
        const int seg = u / HCOLS;
        const int uc  = u - seg * HCOLS;
        const int col = tile_x + uc - HALO;
        const bool cvalid = ((unsigned)col < IMG);
        const int or0 = seg * RPT1;           // first output row (tile coords)
        const int gr0 = tile_y + or0 - HALO;  // first input row

        // Load all 14 input row-pairs first (28 independent loads in
        // flight), then transform. Arrays statically indexed -> regs.
        v2f t[NROWS];
        if (cvalid && gr0 >= 0 && gr0 + (NROWS - 1) < IMG) {
            // interior fast path (wave-uniform for ~70% of tiles)
            const float* __restrict__ cpp = cp + (size_t)gr0 * IMG + col;
            const float* __restrict__ app = ap + (size_t)gr0 * IMG + col;
            float xs[NROWS], ys[NROWS];
            #pragma unroll
            for (int j = 0; j < NROWS; ++j) {
                xs[j] = cpp[j * IMG];
                ys[j] = app[j * IMG];
            }
            #pragma unroll
            for (int j = 0; j < NROWS; ++j)
                t[j] = (v2f){xs[j] + ys[j], xs[j] - ys[j]};
        } else {
            #pragma unroll
            for (int j = 0; j < NROWS; ++j) {
                const int gr = gr0 + j;
                v2f v = {0.f, 0.f};
                if (cvalid && (unsigned)gr < IMG) {
                    const int gi = gr * IMG + col;
                    const float x = cp[gi];
                    const float y = ap[gi];
                    v = (v2f){x + y, x - y};
                }
                t[j] = v;
            }
        }

        v2f accA[RPT1], accB[RPT1];
        #pragma unroll
        for (int o = 0; o < RPT1; ++o) {
            accA[o] = (v2f){0.f, 0.f};
            accB[o] = (v2f){0.f, 0.f};
        }
        #pragma unroll
        for (int j = 0; j < NROWS; ++j) {
            const v2f tv = t[j];
            const v2f p = tv * tv;            // {s^2, d^2}
            #pragma unroll
            for (int o = 0; o < RPT1; ++o) {
                const int kv = j - o;
                if (kv >= 0 && kv < 11) {
                    const float w = WT[kv];
                    accA[o] += w * tv;
                    accB[o] += w * p;
                }
            }
        }

        #pragma unroll
        for (int o = 0; o < RPT1; ++o) {
            hbuf[(or0 + o) * HSTRIDE + uc] =
                (v4f){accA[o].x, accA[o].y, accB[o].x, accB[o].y};
        }
    }
    __syncthreads();

    // ---- Pass 2: horizontal conv, LDS -> regs, + SSIM + reduce ----
    // thread: row = tid&15, col-seg cs = tid>>4 (4 output cols each).
    // 8-lane phase groups: (3*row)%8 over 8 consecutive rows hits all 8
    // bank-quads -> conflict-free b128 reads.
    const int row = tid & 15;
    const int cs  = tid >> 4;                 // 0..15
    const int c0  = cs * 4;                   // output cols c0..c0+3
    const v4f* __restrict__ hrow = hbuf + row * HSTRIDE + c0;

    v2f A[4], B[4];
    #pragma unroll
    for (int o = 0; o < 4; ++o) {
        A[o] = (v2f){0.f, 0.f};
        B[o] = (v2f){0.f, 0.f};
    }

    #pragma unroll
    for (int k = 0; k < 14; ++k) {            // h cols c0+k, k=0..13
        const v4f h = hrow[k];
        const v2f hA = {h.x, h.y};
        const v2f hB = {h.z, h.w};
        #pragma unroll
        for (int o = 0; o < 4; ++o) {
            const int kh = k - o;
            if (kh >= 0 && kh < 11) {
                const float w = WT[kh];
                A[o] += w * hA;
                B[o] += w * hB;
            }
        }
    }

    // u=conv2(s), v=conv2(d), P=conv2(s^2), Q=conv2(d^2), U=u^2, V=v^2:
    //   2*mu12        = (U-V)/2        mu1^2+mu2^2  = (U+V)/2
    //   2*sigma12     = (P-Q)/2-(U-V)/2
    //   sig1^2+sig2^2 = (P+Q)/2-(U+V)/2
    const float C1 = 1e-4f;   // 0.01^2
    const float C2 = 9e-4f;   // 0.03^2
    float lsum = 0.f;
    #pragma unroll
    for (int o = 0; o < 4; ++o) {
        const float U = A[o].x * A[o].x;
        const float V = A[o].y * A[o].y;
        const float halfUmV = 0.5f * (U - V);
        const float halfUpV = 0.5f * (U + V);
        const float num1 = halfUmV + C1;
        const float num2 = 0.5f * (B[o].x - B[o].y) - halfUmV + C2;
        const float den1 = halfUpV + C1;
        const float den2 = 0.5f * (B[o].x + B[o].y) - halfUpV + C2;
        lsum += (num1 * num2) * __builtin_amdgcn_rcpf(den1 * den2);
    }

    // ---- Reduce: wave shuffle -> LDS -> one atomic per block ----
    #pragma unroll
    for (int off = 32; off > 0; off >>= 1)
        lsum += __shfl_down(lsum, off);
    const int lane = tid & 63;
    const int wave = tid >> 6;                // 0..3
    if (lane == 0) wpart[wave] = lsum;
    __syncthreads();
    if (tid == 0) {
        float bs = 0.f;
        #pragma unroll
        for (int w = 0; w < 4; ++w) bs += wpart[w];
        atomicAdd(accum, (double)bs);
    }
}

__global__ void ssim_finalize(const double* __restrict__ accum,
                              float* __restrict__ out)
{
    if (threadIdx.x == 0) {
        out[0] = 1.f - (float)(accum[0] / NPIX);
    }
}

extern "C" void kernel_launch(void* const* d_in, const int* in_sizes, int n_in,
                              void* d_out, int out_size, void* d_ws, size_t ws_size,
                              hipStream_t stream)
{
    const float* clean = (const float*)d_in[0];
    const float* adv   = (const float*)d_in[1];
    float* out = (float*)d_out;
    double* accum = (double*)d_ws;

    hipMemsetAsync(accum, 0, sizeof(double), stream);

    const int nblocks = 96 * 256;  // 96 planes * (8x32 tiles of 64x16)
    ssim_main<<<nblocks, 256, 0, stream>>>(clean, adv, accum);
    ssim_finalize<<<1, 64, 0, stream>>>(accum, out);
}

// Round 8
// 453.096 us; speedup vs baseline: 1.0011x; 1.0011x over previous
//
#include <hip/hip_runtime.h>

// SSIM loss, THREE-phase separable conv, all compute phases LDS-only.
// 96 planes of 512x512. 64x16 tile, 512 threads, 24576 blocks.
//
// R11 post-mortem: batched pass-1 global loads were re-serialized by the
// allocator (VGPR 24!) -> 313us. Across R5-R11, every structure whose
// compute phase reads GLOBAL stalls at 28-38% VALUBusy; the only 70%-busy
// structure measured (R4) stages once to LDS and then computes from
// LDS/regs only. R12 keeps the two-pass FLOP saving but feeds pass V
// from LDS:
//   Phase 0 stage:  raw {s=x+y, d=x-y} global -> LDS  (26x74 px, cheap)
//   Phase 1 vert:   LDS stage -> LDS h[16][74] {vA.s,vA.d,vB.s2,vB.d2}
//                   unit = (col, 2-row seg): 592 units, 12 b64 reads,
//                   56 v2f FMA each. LDS latency (~120cy) hides easily.
//   Phase 2 horiz:  LDS h -> regs, thread = (row, 2-col seg);
//                   12 contiguous b128 reads; 44 v2f FMA + SSIM formula.
// LDS: stage 26x76 v2f = 15.8KB + h 16x75 v4f = 19.2KB = 35KB
//   -> 4 blocks/CU x 8 waves = 32 waves/CU (best residency so far), with
//   zero global-latency exposure after phase 0.
// Bank checks: stage b64 stride-8B consecutive -> 2 lanes/bank (free).
//   h writes b128 stride-16B consecutive -> 8-lane phase covers 8 quads.
//   h reads: quad = (3*row + 2*cs + k) mod 8; lanes 0..7 = rows 0..7 ->
//   {0,3,6,1,4,7,2,5} = all 8 quads -> conflict-free.
// No waves_per_eu attribute: LDS caps at 8 waves/EU anyway; default
// allocator targets the 64-reg budget it has always hit cleanly (R9/R10),
// and with only-LDS latencies that schedule is sufficient.

typedef float v2f __attribute__((ext_vector_type(2)));
typedef float v4f __attribute__((ext_vector_type(4)));

#define IMG 512
#define TW 64               // tile width  (output cols)
#define TH 16               // tile height (output rows)
#define HALO 5
#define SROWS 26            // TH + 2*HALO staged rows
#define SCOLS 74            // TW + 2*HALO staged cols
#define SSTRIDE 76          // stage stride in v2f units
#define HSTRIDE 75          // h stride in v4f units
#define RPTV 2              // pass-V output rows per unit
#define VSEGS 8             // TH / RPTV
#define NPIX 25165824.0     // 32*3*512*512

// Gaussian(sigma=1.5, 11 taps), normalized, fp32 (verified R1-R11)
__device__ constexpr float WT[11] = {
    0.00102838f, 0.00759876f, 0.03600077f, 0.10936068f, 0.21300552f,
    0.26601173f,
    0.21300552f, 0.10936068f, 0.03600077f, 0.00759876f, 0.00102838f};

__global__ __launch_bounds__(512)
void ssim_main(const float* __restrict__ clean,
               const float* __restrict__ adv,
               double* __restrict__ accum)
{
    __shared__ __align__(16) v2f stg[SROWS * SSTRIDE];   // 15,808 B
    __shared__ __align__(16) v4f hbuf[TH * HSTRIDE];     // 19,200 B
    __shared__ float wpart[8];

    const int tid = threadIdx.x;
    const int b = blockIdx.x;
    const int plane = b >> 8;             // 256 tiles per plane
    const int t8 = b & 255;
    const int tile_x = (t8 & 7) * TW;     // 8 tiles across
    const int tile_y = (t8 >> 3) * TH;    // 32 tiles down

    const float* __restrict__ cp = clean + (size_t)plane * (IMG * IMG);
    const float* __restrict__ ap = adv   + (size_t)plane * (IMG * IMG);

    // ---- Phase 0: stage {s,d} global -> LDS (zero-padded at edges) ----
    for (int idx = tid; idx < SROWS * SCOLS; idx += 512) {
        const int r = idx / SCOLS;
        const int c = idx - r * SCOLS;
        const int gr = tile_y + r - HALO;
        const int gc = tile_x + c - HALO;
        v2f v = {0.f, 0.f};
        if ((unsigned)gr < IMG && (unsigned)gc < IMG) {
            const int gi = gr * IMG + gc;
            const float x = cp[gi];
            const float y = ap[gi];
            v = (v2f){x + y, x - y};
        }
        stg[r * SSTRIDE + c] = v;
    }
    __syncthreads();

    // ---- Phase 1: vertical conv, LDS stage -> LDS h ----
    // unit u: seg = u/74 (h rows seg*2, seg*2+1), uc = u%74 (h col).
    // h row o (image row tile_y+o) needs stage rows o..o+10.
    for (int u = tid; u < SCOLS * VSEGS; u += 512) {
        const int seg = u / SCOLS;
        const int uc  = u - seg * SCOLS;
        const int or0 = seg * RPTV;

        v2f accA[RPTV], accB[RPTV];
        #pragma unroll
        for (int o = 0; o < RPTV; ++o) {
            accA[o] = (v2f){0.f, 0.f};
            accB[o] = (v2f){0.f, 0.f};
        }
        #pragma unroll
        for (int j = 0; j < RPTV + 10; ++j) {           // stage rows or0+j
            const v2f t = stg[(or0 + j) * SSTRIDE + uc];
            const v2f p = t * t;                        // {s^2, d^2}
            #pragma unroll
            for (int o = 0; o < RPTV; ++o) {
                const int kv = j - o;
                if (kv >= 0 && kv < 11) {
                    const float w = WT[kv];
                    accA[o] += w * t;
                    accB[o] += w * p;
                }
            }
        }
        #pragma unroll
        for (int o = 0; o < RPTV; ++o) {
            hbuf[(or0 + o) * HSTRIDE + uc] =
                (v4f){accA[o].x, accA[o].y, accB[o].x, accB[o].y};
        }
    }
    __syncthreads();

    // ---- Phase 2: horizontal conv, LDS h -> regs, + SSIM + reduce ----
    // thread: row = tid&15, col-seg cs = tid>>4 (2 output cols each).
    const int row = tid & 15;
    const int cs  = tid >> 4;                 // 0..31
    const int c0  = cs * 2;                   // output cols c0, c0+1
    const v4f* __restrict__ hrow = hbuf + row * HSTRIDE + c0;

    v2f A[2], B[2];
    #pragma unroll
    for (int o = 0; o < 2; ++o) {
        A[o] = (v2f){0.f, 0.f};
        B[o] = (v2f){0.f, 0.f};
    }
    #pragma unroll
    for (int k = 0; k < 12; ++k) {            // h cols c0+k, k=0..11
        const v4f h = hrow[k];
        const v2f hA = {h.x, h.y};
        const v2f hB = {h.z, h.w};
        #pragma unroll
        for (int o = 0; o < 2; ++o) {
            const int kh = k - o;
            if (kh >= 0 && kh < 11) {
                const float w = WT[kh];
                A[o] += w * hA;
                B[o] += w * hB;
            }
        }
    }

    // u=conv2(s), v=conv2(d), P=conv2(s^2), Q=conv2(d^2), U=u^2, V=v^2:
    //   2*mu12        = (U-V)/2        mu1^2+mu2^2  = (U+V)/2
    //   2*sigma12     = (P-Q)/2-(U-V)/2
    //   sig1^2+sig2^2 = (P+Q)/2-(U+V)/2
    const float C1 = 1e-4f;   // 0.01^2
    const float C2 = 9e-4f;   // 0.03^2
    float lsum = 0.f;
    #pragma unroll
    for (int o = 0; o < 2; ++o) {
        const float U = A[o].x * A[o].x;
        const float V = A[o].y * A[o].y;
        const float halfUmV = 0.5f * (U - V);
        const float halfUpV = 0.5f * (U + V);
        const float num1 = halfUmV + C1;
        const float num2 = 0.5f * (B[o].x - B[o].y) - halfUmV + C2;
        const float den1 = halfUpV + C1;
        const float den2 = 0.5f * (B[o].x + B[o].y) - halfUpV + C2;
        lsum += (num1 * num2) * __builtin_amdgcn_rcpf(den1 * den2);
    }

    // ---- Reduce: wave shuffle -> LDS -> one atomic per block ----
    #pragma unroll
    for (int off = 32; off > 0; off >>= 1)
        lsum += __shfl_down(lsum, off);
    const int lane = tid & 63;
    const int wave = tid >> 6;                // 0..7
    if (lane == 0) wpart[wave] = lsum;
    __syncthreads();
    if (tid == 0) {
        float bs = 0.f;
        #pragma unroll
        for (int w = 0; w < 8; ++w) bs += wpart[w];
        atomicAdd(accum, (double)bs);
    }
}

__global__ void ssim_finalize(const double* __restrict__ accum,
                              float* __restrict__ out)
{
    if (threadIdx.x == 0) {
        out[0] = 1.f - (float)(accum[0] / NPIX);
    }
}

extern "C" void kernel_launch(void* const* d_in, const int* in_sizes, int n_in,
                              void* d_out, int out_size, void* d_ws, size_t ws_size,
                              hipStream_t stream)
{
    const float* clean = (const float*)d_in[0];
    const float* adv   = (const float*)d_in[1];
    float* out = (float*)d_out;
    double* accum = (double*)d_ws;

    hipMemsetAsync(accum, 0, sizeof(double), stream);

    const int nblocks = 96 * 256;  // 96 planes * (8x32 tiles of 64x16)
    ssim_main<<<nblocks, 512, 0, stream>>>(clean, adv, accum);
    ssim_finalize<<<1, 64, 0, stream>>>(accum, out);
}